// Round 1
// baseline (359.055 us; speedup 1.0000x reference)
//
#include <hip/hip_runtime.h>

// u1[bc[k]] = w1[k] * u[bc[k]]
__global__ void scatter_u1_kernel(const float* __restrict__ u,
                                  const float* __restrict__ w1,
                                  const int* __restrict__ bc,
                                  float* __restrict__ u1, int n) {
    int k = blockIdx.x * blockDim.x + threadIdx.x;
    if (k < n) {
        int idx = bc[k];
        u1[idx] = w1[k] * u[idx];
    }
}

// 8 threads per element. Thread i of element e:
//   - loads edof[e*8+i] (coalesced int32)
//   - gathers ue_i = u1[idx] (random 4B, L2/L3-resident: u1 is 4 MB)
//   - loads stiffness row i as 2x float4 (8 lanes cover 256B contiguous)
//   - fe_i = sum_j K[i][j] * ue_j  with ue_j broadcast via __shfl width=8
//   - atomicAdd(&F[idx], fe_i)
__global__ void elem_assemble_kernel(const float* __restrict__ u1,
                                     const int* __restrict__ edof,
                                     const float* __restrict__ stiff,
                                     float* __restrict__ F, int nelem) {
    int t = blockIdx.x * blockDim.x + threadIdx.x;
    int e = t >> 3;
    if (e >= nelem) return;
    int i = t & 7;

    int idx = edof[t];            // edof[e*8 + i]
    float ue = u1[idx];

    const float4* Kr = (const float4*)(stiff + (size_t)e * 64 + (size_t)i * 8);
    float4 k0 = Kr[0];
    float4 k1 = Kr[1];

    float fe;
    fe  = k0.x * __shfl(ue, 0, 8);
    fe += k0.y * __shfl(ue, 1, 8);
    fe += k0.z * __shfl(ue, 2, 8);
    fe += k0.w * __shfl(ue, 3, 8);
    fe += k1.x * __shfl(ue, 4, 8);
    fe += k1.y * __shfl(ue, 5, 8);
    fe += k1.z * __shfl(ue, 6, 8);
    fe += k1.w * __shfl(ue, 7, 8);

    atomicAdd(&F[idx], fe);
}

extern "C" void kernel_launch(void* const* d_in, const int* in_sizes, int n_in,
                              void* d_out, int out_size, void* d_ws, size_t ws_size,
                              hipStream_t stream) {
    const float* u     = (const float*)d_in[0];
    const float* w1    = (const float*)d_in[1];
    const int*   bc    = (const int*)d_in[2];
    const int*   edof  = (const int*)d_in[3];
    const float* stiff = (const float*)d_in[4];
    float* F  = (float*)d_out;
    float* u1 = (float*)d_ws;

    int ndof  = in_sizes[0];
    int nbc   = in_sizes[2];
    int nelem = in_sizes[3] / 8;

    // d_out and d_ws are poisoned 0xAA before every launch — zero them.
    hipMemsetAsync(F,  0, (size_t)ndof * sizeof(float), stream);
    hipMemsetAsync(u1, 0, (size_t)ndof * sizeof(float), stream);

    scatter_u1_kernel<<<(nbc + 255) / 256, 256, 0, stream>>>(u, w1, bc, u1, nbc);

    int total = nelem * 8;
    elem_assemble_kernel<<<(total + 255) / 256, 256, 0, stream>>>(
        u1, edof, stiff, F, nelem);
}